// Round 9
// baseline (101.191 us; speedup 1.0000x reference)
//
#include <hip/hip_runtime.h>
#include <hip/hip_bf16.h>
#include <stdint.h>

// KANLinear: y[b,o] = sum_{d,k} coeff[b,d,k]*values[o,d,k] + xc@skip_w^T + skip_b
//   Vp[o,d*16+k] = values[o,d,k] + grid[k]*skip_w[o,d]   (prep, bf16)
//   y = A @ Vp^T + skip_b  (MFMA GEMM  M=8192 N=256 K=4096)
// Round 9: KS=2 (1 block/CU -> half the per-CU L2 demand; tests L2-saturation
//          hypothesis) + fused last-block finisher (threadfence + atomic
//          counter) kills the separate reduce kernel and its 40MB round-trip.
//          Barrier-free K-loop (R8 Pk in-register A decode), Pk = 64KB window
//          rebuilt once mid-loop. B direct from L2 (chunk-transposed Vp).

#define D_DIM  256
#define O_DIM  256
#define BM     128
#define ITERS  32            // K-slice 2048 / BK 64
#define NTHR   256

typedef __attribute__((ext_vector_type(8))) short bf16x8;
typedef __attribute__((ext_vector_type(4))) float f32x4;

// ---------------------------------------------------------------------------
// Prep (proven R6-R8): Vp chunk-transposed: chunk c = kflat>>3 (16B of 8
// bf16) stored at Vp[(c*256 + o)*8] -> B-fragment load is 256B-coalesced.
// ---------------------------------------------------------------------------
__global__ __launch_bounds__(256) void kan_prep(
    const float* __restrict__ values,   // [O][D][K]
    const float* __restrict__ skip_w,   // [O][D]
    const float* __restrict__ gknots,   // [K]
    unsigned short* __restrict__ Vp)    // 2 MB bf16, chunk-transposed
{
    int tid = blockIdx.x * blockDim.x + threadIdx.x;    // 0..131071
    int e = tid * 8;
    int o = e >> 12;
    int kflat = e & 4095;
    float sw = skip_w[(o << 8) | (kflat >> 4)];
    int kmod = kflat & 15;                              // 0 or 8

    const float4* vp4 = reinterpret_cast<const float4*>(values + e);
    float4 v0 = vp4[0], v1 = vp4[1];
    float f[8] = {v0.x, v0.y, v0.z, v0.w, v1.x, v1.y, v1.z, v1.w};
    unsigned int w[4];
#pragma unroll
    for (int j = 0; j < 4; ++j) {
        float2 ab;
        ab.x = f[2*j]     + gknots[kmod + 2*j]     * sw;
        ab.y = f[2*j + 1] + gknots[kmod + 2*j + 1] * sw;
        __hip_bfloat162 p2 = __float22bfloat162_rn(ab);
        __builtin_memcpy(&w[j], &p2, 4);
    }
    size_t c = (size_t)(kflat >> 3) * 256 + (size_t)o;
    *reinterpret_cast<uint4*>(Vp + c * 8) = make_uint4(w[0], w[1], w[2], w[3]);
}

// ---------------------------------------------------------------------------
// GEMM + fused finisher. BM=128 x BN=128 x BK=64, 4 waves (2wm x 2wn),
// wave-tile 64x64. KS=2: block ks covers K = [ks*2048, +2048) (d-range
// ks*128..+128, two 64-d Pk windows). Grid 256 = 1 block/CU.
// ---------------------------------------------------------------------------
__global__ __launch_bounds__(NTHR, 1) void kan_gemm(
    const float* __restrict__ x,          // [B][D] f32
    const unsigned short* __restrict__ Vp,
    const float* __restrict__ skip_b,     // [O]
    float* __restrict__ part,             // [2][8192][256] f32
    int* __restrict__ cnt,                // [64][2] zeroed per launch
    float* __restrict__ out)              // [8192][256] f32
{
    __shared__ unsigned long long Pk[128 * 64];   // 64 KB window
    __shared__ int sflag;

    const int t    = threadIdx.x;
    const int lane = t & 63;
    const int wid  = t >> 6;
    const int wm   = wid >> 1;         // 0..1 (64 rows)
    const int wn   = wid & 1;          // 0..1 (64 cols)
    const int l15  = lane & 15;
    const int lhi  = lane >> 4;        // 0..3

    const int bid = (int)blockIdx.x;
    const int ks  = bid & 1;
    const int nt  = (bid >> 1) & 1;
    const int mt  = bid >> 2;
    const int bm0 = mt * BM;
    const int nc0 = nt * 128;
    const size_t kc0 = (size_t)ks * 256;   // global 16B-chunk base

    char* pb = (char*)&Pk[0];

    // Pk window build: thread t -> row t>>1, d-half (t&1)*32 of 64-d window w
    auto buildPk = [&](int w) {
        int row = t >> 1;
        int half = (t & 1) * 32;
        const float* xr = x + (size_t)(bm0 + row) * D_DIM + ks * 128 + w * 64 + half;
        int rs = (row & 7) << 2;
#pragma unroll
        for (int j4 = 0; j4 < 8; ++j4) {
            float4 xv = reinterpret_cast<const float4*>(xr)[j4];
            float v[4] = {xv.x, xv.y, xv.z, xv.w};
#pragma unroll
            for (int e = 0; e < 4; ++e) {
                int dloc = half + j4 * 4 + e;              // 0..63
                float xc = fminf(1.f, fmaxf(-1.f, v[e]));
                float tt = (xc + 1.f) * 7.5f;              // (xc-g0)/h, h=2/15
                int li = (int)tt;
                li = li > 14 ? 14 : li;
                float w1 = tt - (float)li;
                float2 cw; cw.x = 1.f - w1; cw.y = w1;
                __hip_bfloat162 p2 = __float22bfloat162_rn(cw);
                unsigned int pkw;
                __builtin_memcpy(&pkw, &p2, 4);
                unsigned long long q8 =
                    ((unsigned long long)pkw << ((li & 1) << 4)) |
                    ((unsigned long long)(unsigned)(li >> 1) << 48);
                int kt = dloc >> 2, p = (dloc >> 1) & 1, g2 = dloc & 1;
                int s = kt * 2 + g2;
                *reinterpret_cast<unsigned long long*>(
                    pb + row * 512 + ((s ^ rs) << 4) + p * 8) = q8;
            }
        }
    };

    // per-lane constants
    const unsigned jbase = (unsigned)((lhi & 1) * 4);
    const int g = lhi >> 1;
    int prow[4], prs[4];
#pragma unroll
    for (int mi = 0; mi < 4; ++mi) {
        int row = wm * 64 + mi * 16 + l15;
        prow[mi] = row * 512;
        prs[mi] = (row & 7) << 2;
    }

    #define LOADB(BG, KT)                                                      \
        {                                                                      \
            const unsigned short* _b = Vp + (kc0 + (size_t)(KT) * 8) * 2048;   \
            _Pragma("unroll")                                                  \
            for (int kh = 0; kh < 2; ++kh)                                     \
                _Pragma("unroll")                                              \
                for (int ni = 0; ni < 4; ++ni) {                               \
                    int n = nc0 + wn * 64 + ni * 16 + l15;                     \
                    BG[kh * 4 + ni] = *reinterpret_cast<const bf16x8*>(        \
                        _b + ((size_t)((kh * 4 + lhi) * 256 + n)) * 8);        \
                }                                                              \
        }

    auto mkfrag = [&](unsigned lo, unsigned hi) -> bf16x8 {
        unsigned jd = (hi >> 16) - jbase;
        unsigned hc = hi & 0xffffu;
        uint4 w;
        w.x = (jd == 0u) ? lo : ((jd + 1u == 0u) ? hc : 0u);
        w.y = (jd == 1u) ? lo : ((jd == 0u) ? hc : 0u);
        w.z = (jd == 2u) ? lo : ((jd == 1u) ? hc : 0u);
        w.w = (jd == 3u) ? lo : ((jd == 2u) ? hc : 0u);
        bf16x8 r;
        __builtin_memcpy(&r, &w, 16);
        return r;
    };

    f32x4 acc[4][4] = {};
    bf16x8 bgA[8], bgB[8];

    buildPk(0);
    __syncthreads();
    LOADB(bgA, 0);

    #define ITERBODY(KT, BGC, BGN)                                            \
        {                                                                     \
            const bool last = (KT) == ITERS - 1;                              \
            if (!last) LOADB(BGN, (KT) + 1);                                  \
            uint4 q[4];                                                       \
            _Pragma("unroll")                                                 \
            for (int mi = 0; mi < 4; ++mi)                                    \
                q[mi] = *reinterpret_cast<const uint4*>(                      \
                    pb + prow[mi] + (((((KT) & 15) * 2 + g) ^ prs[mi]) << 4));\
            bf16x8 af[4];                                                     \
            _Pragma("unroll")                                                 \
            for (int mi = 0; mi < 4; ++mi)                                    \
                af[mi] = mkfrag(q[mi].x, q[mi].y);                            \
            __builtin_amdgcn_s_setprio(1);                                    \
            _Pragma("unroll")                                                 \
            for (int mi = 0; mi < 4; ++mi)                                    \
                _Pragma("unroll")                                             \
                for (int ni = 0; ni < 4; ++ni)                                \
                    acc[mi][ni] = __builtin_amdgcn_mfma_f32_16x16x32_bf16(    \
                        af[mi], BGC[ni], acc[mi][ni], 0, 0, 0);               \
            __builtin_amdgcn_s_setprio(0);                                    \
            _Pragma("unroll")                                                 \
            for (int mi = 0; mi < 4; ++mi)                                    \
                af[mi] = mkfrag(q[mi].z, q[mi].w);                            \
            __builtin_amdgcn_s_setprio(1);                                    \
            _Pragma("unroll")                                                 \
            for (int mi = 0; mi < 4; ++mi)                                    \
                _Pragma("unroll")                                             \
                for (int ni = 0; ni < 4; ++ni)                                \
                    acc[mi][ni] = __builtin_amdgcn_mfma_f32_16x16x32_bf16(    \
                        af[mi], BGC[4 + ni], acc[mi][ni], 0, 0, 0);           \
            __builtin_amdgcn_s_setprio(0);                                    \
        }

    for (int t2 = 0; t2 < ITERS / 2; ++t2) {
        if (t2 == ITERS / 4) {              // kt 16: swap Pk window
            __syncthreads();                // all waves done with window 0
            buildPk(1);
            __syncthreads();
        }
        ITERBODY(2 * t2,     bgA, bgB);
        ITERBODY(2 * t2 + 1, bgB, bgA);
    }
    #undef ITERBODY
    #undef LOADB

    // ---- store partial for this K-slice
    float* dst = part + (size_t)ks * (8192 * 256);
#pragma unroll
    for (int ni = 0; ni < 4; ++ni) {
        int col = nc0 + wn * 64 + ni * 16 + l15;
#pragma unroll
        for (int mi = 0; mi < 4; ++mi) {
            f32x4 v = acc[mi][ni];
            int row0 = bm0 + wm * 64 + mi * 16 + lhi * 4;
#pragma unroll
            for (int r = 0; r < 4; ++r)
                dst[(size_t)(row0 + r) * O_DIM + col] = v[r];
        }
    }

    // ---- fused finisher: last block of the (mt,nt) pair combines
    __threadfence();                               // release partial stores
    if (t == 0) sflag = atomicAdd(&cnt[mt * 2 + nt], 1);
    __syncthreads();
    if (sflag == 1) {                              // second (= last) arrival
        __threadfence();                           // acquire others' stores
        const float* p0 = part;
        const float* p1 = part + (size_t)8192 * 256;
#pragma unroll
        for (int i = 0; i < 16; ++i) {
            int c = t + 256 * i;                   // 0..4095 f32x4 chunks
            int row = bm0 + (c >> 5);
            int col = nc0 + (c & 31) * 4;
            size_t off = (size_t)row * O_DIM + col;
            f32x4 a = *reinterpret_cast<const f32x4*>(p0 + off);
            f32x4 b = *reinterpret_cast<const f32x4*>(p1 + off);
            f32x4 sb = *reinterpret_cast<const f32x4*>(skip_b + col);
            *reinterpret_cast<f32x4*>(out + off) = a + b + sb;
        }
    }
}

// ---------------------------------------------------------------------------
// Naive fallback (tiny workspace only) — correct, slow.
// ---------------------------------------------------------------------------
__global__ __launch_bounds__(256) void kan_naive(
    const float* __restrict__ x,
    const unsigned short* __restrict__ Vp,   // chunk-transposed
    const float* __restrict__ skip_b,
    float* __restrict__ out)
{
    int b = blockIdx.x, o = threadIdx.x;
    float acc = skip_b[o];
    for (int d = 0; d < 256; ++d) {
        float xc = fminf(1.f, fmaxf(-1.f, x[(size_t)b * 256 + d]));
        float tt = (xc + 1.f) * 7.5f;
        int li = (int)tt; li = li > 14 ? 14 : li;
        float w1 = tt - (float)li;
        int k0 = d * 16 + li;
        unsigned short u0 = Vp[((size_t)(k0 >> 3) * 256 + o) * 8 + (k0 & 7)];
        int k1 = k0 + 1;
        unsigned short u1 = Vp[((size_t)(k1 >> 3) * 256 + o) * 8 + (k1 & 7)];
        float f0 = __uint_as_float((unsigned)u0 << 16);
        float f1 = __uint_as_float((unsigned)u1 << 16);
        acc += (1.f - w1) * f0 + w1 * f1;
    }
    out[(size_t)b * 256 + o] = acc;
}

extern "C" void kernel_launch(void* const* d_in, const int* in_sizes, int n_in,
                              void* d_out, int out_size, void* d_ws, size_t ws_size,
                              hipStream_t stream) {
    const float* x      = (const float*)d_in[0];   // [8192][256]
    const float* values = (const float*)d_in[1];   // [256][256][16]
    const float* skip_w = (const float*)d_in[2];   // [256][256]
    const float* skip_b = (const float*)d_in[3];   // [256]
    const float* gknots = (const float*)d_in[4];   // [16]
    float* out = (float*)d_out;
    (void)in_sizes; (void)n_in; (void)out_size;

    unsigned short* Vp = (unsigned short*)d_ws;                         // 2 MB
    float* part = (float*)((char*)d_ws + 2u * 1024 * 1024);             // 16 MB
    int* cnt = (int*)((char*)d_ws + 2u * 1024 * 1024
                      + (size_t)2 * 8192 * 256 * sizeof(float));        // 512 B

    kan_prep<<<dim3(512), dim3(256), 0, stream>>>(values, skip_w, gknots, Vp);

    const size_t need = 2u * 1024 * 1024
                      + (size_t)2 * 8192 * 256 * sizeof(float) + 512;
    if (ws_size >= need) {
        hipMemsetAsync(cnt, 0, 128 * sizeof(int), stream);
        // 64 mt x 2 nt x 2 ks = 256 blocks = 1/CU
        kan_gemm<<<dim3(256), dim3(NTHR), 0, stream>>>(
            x, Vp, skip_b, part, cnt, out);
    } else {
        kan_naive<<<dim3(8192), dim3(256), 0, stream>>>(x, Vp, skip_b, out);
    }
}